// Round 2
// baseline (3366.719 us; speedup 1.0000x reference)
//
#include <hip/hip_runtime.h>

#define B_ 64
#define T_ 512
#define E_ 512
#define HD_ 256
#define H_ 512
#define K_ 16
#define NEG_ (-10000.0f)
#define START_ 13
#define STOP_ 14

typedef unsigned int u32;
using half8  = __attribute__((ext_vector_type(8))) _Float16;
using f32x4  = __attribute__((ext_vector_type(4))) float;
using half2v = __attribute__((ext_vector_type(2))) _Float16;

__device__ __forceinline__ float dot2h(u32 a, u32 b, float c) {
#if __has_builtin(__builtin_amdgcn_fdot2)
    return __builtin_amdgcn_fdot2(__builtin_bit_cast(half2v, a),
                                  __builtin_bit_cast(half2v, b), c, false);
#else
    half2v ha = __builtin_bit_cast(half2v, a), hb = __builtin_bit_cast(half2v, b);
    return c + (float)ha.x * (float)hb.x + (float)ha.y * (float)hb.y;
#endif
}
__device__ __forceinline__ float sigm(float x) { return 1.f / (1.f + __expf(-x)); }
__device__ __forceinline__ float tanh_f(float x) {
    float a = fabsf(x);
    float e = __expf(-2.f * a);
    float t = (1.f - e) / (1.f + e);
    return x < 0.f ? -t : t;
}

// ---------------- converters ----------------
__global__ void cvt_f16_k(const float* __restrict__ src, _Float16* __restrict__ dst, int n4) {
    int i = blockIdx.x * blockDim.x + threadIdx.x;
    if (i < n4) {
        float4 v = ((const float4*)src)[i];
        half2v a; a.x = (_Float16)v.x; a.y = (_Float16)v.y;
        half2v b; b.x = (_Float16)v.z; b.y = (_Float16)v.w;
        ((u32*)dst)[2 * i]     = __builtin_bit_cast(u32, a);
        ((u32*)dst)[2 * i + 1] = __builtin_bit_cast(u32, b);
    }
}
__global__ void bias_sum_k(const float* __restrict__ bih, const float* __restrict__ bhh,
                           float* __restrict__ bs) {
    int i = blockIdx.x * blockDim.x + threadIdx.x;
    if (i < 4096) bs[i] = bih[i] + bhh[i];
}

// ---------------- embedding gather + cast to f16 ----------------
__global__ void embed_k(const int* __restrict__ x, const float* __restrict__ emb,
                        _Float16* __restrict__ xe) {
    int m = blockIdx.x;                  // 0..32767 = b*T + t
    int row = x[m];
    int c = threadIdx.x * 4;             // 128 threads * 4 = 512
    float4 v = *(const float4*)(emb + (size_t)row * E_ + c);
    half2v p0; p0.x = (_Float16)v.x; p0.y = (_Float16)v.y;
    half2v p1; p1.x = (_Float16)v.z; p1.y = (_Float16)v.w;
    u32* dst = (u32*)(xe + (size_t)m * E_) + threadIdx.x * 2;
    dst[0] = __builtin_bit_cast(u32, p0);
    dst[1] = __builtin_bit_cast(u32, p1);
}

// ---------------- f16 MFMA GEMM:  C[m,n] = sum_k A[m,k]*Bw[n,k] + bias[n]  (C f16) -----
__global__ __launch_bounds__(256) void gemm_bt(const _Float16* __restrict__ A,
                                               const _Float16* __restrict__ Bw,
                                               const float* __restrict__ bsum,
                                               _Float16* __restrict__ C,
                                               int M, int N, int Kd) {
    __shared__ __align__(16) _Float16 As[128 * 64];
    __shared__ __align__(16) _Float16 Bs[128 * 64];
    const int nTn = N >> 7;
    const int tm = blockIdx.x / nTn, tn = blockIdx.x % nTn;
    const int tid = threadIdx.x;
    const int lane = tid & 63, wave = tid >> 6;
    const int wr = wave >> 1, wc = wave & 1;      // 2x2 waves of 64x64
    f32x4 acc[4][4];
#pragma unroll
    for (int i = 0; i < 4; ++i)
#pragma unroll
        for (int j = 0; j < 4; ++j) acc[i][j] = f32x4{0.f, 0.f, 0.f, 0.f};
    const int lr = lane & 15, lk = (lane >> 4) * 8;

    for (int k0 = 0; k0 < Kd; k0 += 64) {
#pragma unroll
        for (int r = 0; r < 4; ++r) {
            int c = r * 256 + tid;                     // chunk id, 16B each
            const _Float16* srcA = A + (size_t)(tm * 128 + (c >> 3)) * Kd + k0 + (c & 7) * 8;
            const _Float16* srcB = Bw + (size_t)(tn * 128 + (c >> 3)) * Kd + k0 + (c & 7) * 8;
            _Float16* dA = &As[(size_t)(r * 256 + wave * 64) * 8];
            _Float16* dB = &Bs[(size_t)(r * 256 + wave * 64) * 8];
            __builtin_amdgcn_global_load_lds((const __attribute__((address_space(1))) void*)srcA,
                                             (__attribute__((address_space(3))) void*)dA, 16, 0, 0);
            __builtin_amdgcn_global_load_lds((const __attribute__((address_space(1))) void*)srcB,
                                             (__attribute__((address_space(3))) void*)dB, 16, 0, 0);
        }
        __syncthreads();
#pragma unroll
        for (int kk = 0; kk < 2; ++kk) {
            half8 av[4], bv[4];
#pragma unroll
            for (int i = 0; i < 4; ++i)
                av[i] = *(const half8*)&As[(wr * 64 + i * 16 + lr) * 64 + kk * 32 + lk];
#pragma unroll
            for (int j = 0; j < 4; ++j)
                bv[j] = *(const half8*)&Bs[(wc * 64 + j * 16 + lr) * 64 + kk * 32 + lk];
#pragma unroll
            for (int i = 0; i < 4; ++i)
#pragma unroll
                for (int j = 0; j < 4; ++j)
                    acc[i][j] = __builtin_amdgcn_mfma_f32_16x16x32_f16(av[i], bv[j], acc[i][j], 0, 0, 0);
        }
        __syncthreads();
    }
    const int mq = (lane >> 4) * 4;
#pragma unroll
    for (int i = 0; i < 4; ++i)
#pragma unroll
        for (int j = 0; j < 4; ++j) {
            int m0 = tm * 128 + wr * 64 + i * 16 + mq;
            int n0 = tn * 128 + wc * 64 + j * 16 + lr;
            float bv = bsum[n0];
#pragma unroll
            for (int q = 0; q < 4; ++q)
                C[(size_t)(m0 + q) * N + n0] = (_Float16)(acc[i][j][q] + bv);
        }
}

// ---------------- LSTM recurrence ----------------------------------------------------
// One block per (b, dir), 1024 threads. Thread (wave w, lane l): j = w*16 + (l&15),
// quadrant q = l>>4 owns h-chunk [64q, 64q+64) of the 4 gate rows {j, j+256, j+512, j+768}.
// After a 2-stage shfl_xor butterfly every lane holds the full i,f,g,o preacts for its j
// -> gate math is in-wave, ONE barrier per step. W: 24 u32/row in VGPRs + 8 u32/row in LDS.
#define WREG 24
__global__ __launch_bounds__(1024, 4) void lstm_layer_k(
    const _Float16* __restrict__ whh,     // [2][1024][256] (this layer)
    const float* __restrict__ h0,         // [2][64][256]
    const float* __restrict__ c0,         // [2][64][256]
    const _Float16* __restrict__ Z,       // [32768][2048] f16 gate preacts (x@Wih + bias)
    _Float16* __restrict__ Hout) {        // [32768][512] f16
    __shared__ __align__(16) uint4 wt[8 * 1024];     // 128 KB weight tails: [slot][tid]
    __shared__ __align__(16) u32 h_sh[2][4][36];     // double-buffered h, 36-u32 padded chunks
    const int tid = threadIdx.x;
    const int b = blockIdx.x >> 1, dir = blockIdx.x & 1;
    const int wv = tid >> 6, l = tid & 63;
    const int jj = l & 15, q = l >> 4;
    const int j = wv * 16 + jj;           // 0..255

    // --- load weights: rows g*256+j, h-cols [64q, 64q+64) ---
    const u32*  wbase  = (const u32*)(whh + (size_t)dir * 1024 * 256);
    const uint4* wbase4 = (const uint4*)wbase;
    u32 w0[WREG], w1[WREG], w2[WREG], w3[WREG];
#pragma unroll
    for (int k = 0; k < WREG; ++k) {
        w0[k] = wbase[(size_t)(0 * 256 + j) * 128 + 32 * q + k];
        w1[k] = wbase[(size_t)(1 * 256 + j) * 128 + 32 * q + k];
        w2[k] = wbase[(size_t)(2 * 256 + j) * 128 + 32 * q + k];
        w3[k] = wbase[(size_t)(3 * 256 + j) * 128 + 32 * q + k];
    }
#pragma unroll
    for (int ii = 0; ii < 2; ++ii) {
#pragma unroll
        for (int g = 0; g < 4; ++g)
            wt[(ii * 4 + g) * 1024 + tid] = wbase4[(size_t)(g * 256 + j) * 32 + 8 * q + 6 + ii];
    }
    // --- state init ---
    float c = c0[(size_t)dir * B_ * HD_ + b * HD_ + j];
    if (tid < 128) {
        int p = tid;   // f16-pair index 0..127
        float x0 = h0[(size_t)dir * B_ * HD_ + b * HD_ + 2 * p];
        float x1 = h0[(size_t)dir * B_ * HD_ + b * HD_ + 2 * p + 1];
        half2v hp; hp.x = (_Float16)x0; hp.y = (_Float16)x1;
        h_sh[0][p >> 5][p & 31] = __builtin_bit_cast(u32, hp);
    }
    // --- z prefetch for step 0 (q==0 lanes only) ---
    const _Float16* Zj = Z + (size_t)b * T_ * 2048 + dir * 1024 + j;
    _Float16 z0 = 0, z1 = 0, z2 = 0, z3 = 0;
    {
        int t0 = dir ? (T_ - 1) : 0;
        if (q == 0) {
            const _Float16* zr = Zj + (size_t)t0 * 2048;
            z0 = zr[0]; z1 = zr[256]; z2 = zr[512]; z3 = zr[768];
        }
    }
    __syncthreads();

    int cur = 0;
    for (int s = 0; s < T_; ++s) {
        const int t = dir ? (T_ - 1 - s) : s;
        // prefetch next step's z early (hides HBM/L2 latency under the dot phase)
        _Float16 n0 = 0, n1 = 0, n2 = 0, n3 = 0;
        if (q == 0 && s + 1 < T_) {
            const int tn = dir ? (t - 1) : (t + 1);
            const _Float16* zr = Zj + (size_t)tn * 2048;
            n0 = zr[0]; n1 = zr[256]; n2 = zr[512]; n3 = zr[768];
        }
        // --- 64-wide quarter dots for 4 gate rows ---
        const uint4* hb = (const uint4*)&h_sh[cur][q][0];
        float a0 = 0.f, a1 = 0.f, a2 = 0.f, a3 = 0.f;
#pragma unroll
        for (int i = 0; i < 6; ++i) {
            uint4 hv = hb[i];
            a0 = dot2h(w0[4 * i], hv.x, a0); a0 = dot2h(w0[4 * i + 1], hv.y, a0);
            a0 = dot2h(w0[4 * i + 2], hv.z, a0); a0 = dot2h(w0[4 * i + 3], hv.w, a0);
            a1 = dot2h(w1[4 * i], hv.x, a1); a1 = dot2h(w1[4 * i + 1], hv.y, a1);
            a1 = dot2h(w1[4 * i + 2], hv.z, a1); a1 = dot2h(w1[4 * i + 3], hv.w, a1);
            a2 = dot2h(w2[4 * i], hv.x, a2); a2 = dot2h(w2[4 * i + 1], hv.y, a2);
            a2 = dot2h(w2[4 * i + 2], hv.z, a2); a2 = dot2h(w2[4 * i + 3], hv.w, a2);
            a3 = dot2h(w3[4 * i], hv.x, a3); a3 = dot2h(w3[4 * i + 1], hv.y, a3);
            a3 = dot2h(w3[4 * i + 2], hv.z, a3); a3 = dot2h(w3[4 * i + 3], hv.w, a3);
        }
#pragma unroll
        for (int ii = 0; ii < 2; ++ii) {
            uint4 hv = hb[6 + ii];
            uint4 tw;
            tw = wt[(ii * 4 + 0) * 1024 + tid];
            a0 = dot2h(tw.x, hv.x, a0); a0 = dot2h(tw.y, hv.y, a0);
            a0 = dot2h(tw.z, hv.z, a0); a0 = dot2h(tw.w, hv.w, a0);
            tw = wt[(ii * 4 + 1) * 1024 + tid];
            a1 = dot2h(tw.x, hv.x, a1); a1 = dot2h(tw.y, hv.y, a1);
            a1 = dot2h(tw.z, hv.z, a1); a1 = dot2h(tw.w, hv.w, a1);
            tw = wt[(ii * 4 + 2) * 1024 + tid];
            a2 = dot2h(tw.x, hv.x, a2); a2 = dot2h(tw.y, hv.y, a2);
            a2 = dot2h(tw.z, hv.z, a2); a2 = dot2h(tw.w, hv.w, a2);
            tw = wt[(ii * 4 + 3) * 1024 + tid];
            a3 = dot2h(tw.x, hv.x, a3); a3 = dot2h(tw.y, hv.y, a3);
            a3 = dot2h(tw.z, hv.z, a3); a3 = dot2h(tw.w, hv.w, a3);
        }
        // fold z (already includes biases, from GEMM epilogue) into q0's partial
        a0 += (q == 0) ? (float)z0 : 0.f;
        a1 += (q == 0) ? (float)z1 : 0.f;
        a2 += (q == 0) ? (float)z2 : 0.f;
        a3 += (q == 0) ? (float)z3 : 0.f;
        // butterfly over quadrants: every lane ends with full preacts for its j
        a0 += __shfl_xor(a0, 16, 64); a0 += __shfl_xor(a0, 32, 64);
        a1 += __shfl_xor(a1, 16, 64); a1 += __shfl_xor(a1, 32, 64);
        a2 += __shfl_xor(a2, 16, 64); a2 += __shfl_xor(a2, 32, 64);
        a3 += __shfl_xor(a3, 16, 64); a3 += __shfl_xor(a3, 32, 64);
        // gates (i,f,g,o), redundantly in all 4 quadrant copies
        float ig = sigm(a0), fg = sigm(a1), gg = tanh_f(a2), og = sigm(a3);
        c = fg * c + ig * gg;
        float h = og * tanh_f(c);
        if (q == 0) {
            _Float16 hf = (_Float16)h;
            int p = j >> 1;
            ((_Float16*)&h_sh[cur ^ 1][p >> 5][p & 31])[j & 1] = hf;
            Hout[(size_t)(b * T_ + t) * H_ + dir * HD_ + j] = hf;
        }
        z0 = n0; z1 = n1; z2 = n2; z3 = n3;
        __syncthreads();
        cur ^= 1;
    }
}

// ---------------- tag scores: out[m,kk] = H[m,:] . w_out[kk,:] + b_out[kk] ----------------
__global__ __launch_bounds__(256) void tag_k(const _Float16* __restrict__ Hs,
                                             const float* __restrict__ wout,
                                             const float* __restrict__ bout,
                                             float* __restrict__ out) {
    const int tid = threadIdx.x;
    const int mi = tid >> 4, kk = tid & 15;
    const int m = blockIdx.x * 16 + mi;
    const uint4* hrow = (const uint4*)(Hs + (size_t)m * H_);
    const float4* wrow = (const float4*)(wout + (size_t)kk * H_);
    float acc = 0.f;
#pragma unroll 8
    for (int i = 0; i < 64; ++i) {
        uint4 hv = hrow[i];
        float4 w0 = wrow[2 * i], w1 = wrow[2 * i + 1];
        half2v p0 = __builtin_bit_cast(half2v, hv.x), p1 = __builtin_bit_cast(half2v, hv.y);
        half2v p2 = __builtin_bit_cast(half2v, hv.z), p3 = __builtin_bit_cast(half2v, hv.w);
        acc += (float)p0.x * w0.x + (float)p0.y * w0.y + (float)p1.x * w0.z + (float)p1.y * w0.w
             + (float)p2.x * w1.x + (float)p2.y * w1.y + (float)p3.x * w1.z + (float)p3.y * w1.w;
    }
    out[(size_t)m * K_ + kk] = acc + bout[kk];
}

// ---------------- CRF forward (faithful to reference's cross-batch sum) ----------------
__global__ __launch_bounds__(1024) void crf_k(const float* __restrict__ tag,
                                              const float* __restrict__ trans,
                                              float* __restrict__ out) {
    __shared__ float albuf[2][64][17];
    const int tid = threadIdx.x;
    const int kn = tid >> 6, b = tid & 63;   // wave = next-tag, lane = batch
    float trow[16];
#pragma unroll
    for (int kp = 0; kp < 16; ++kp) trow[kp] = trans[kn * 16 + kp];
    albuf[0][b][kn] = (kn == START_) ? 0.f : NEG_;
    __syncthreads();
    int cur = 0;
    for (int t = 0; t < T_; ++t) {
        const float feat = tag[(size_t)(b * T_ + t) * K_ + kn];
        float v[16];
        float m = -3.4e38f;
#pragma unroll
        for (int kp = 0; kp < 16; ++kp) {
            v[kp] = albuf[cur][b][kp] + trow[kp];
            m = fmaxf(m, v[kp]);
        }
        float sm = 0.f;
#pragma unroll
        for (int kp = 0; kp < 16; ++kp) sm += __expf(v[kp] - m);
#pragma unroll
        for (int off = 32; off >= 1; off >>= 1) sm += __shfl_xor(sm, off, 64);
        albuf[cur ^ 1][b][kn] = feat + m + __logf(sm);
        __syncthreads();
        cur ^= 1;
    }
    const float term = albuf[cur][b][kn] + trans[STOP_ * 16 + kn];
    albuf[cur ^ 1][b][kn] = term;
    __syncthreads();
    if (tid < 64) {   // all in wave 0
        float mb = -3.4e38f;
#pragma unroll
        for (int k2 = 0; k2 < 16; ++k2) mb = fmaxf(mb, albuf[cur ^ 1][tid][k2]);
        float p = 0.f;
#pragma unroll
        for (int k2 = 0; k2 < 16; ++k2) p += __expf(albuf[cur ^ 1][tid][k2] - mb);
#pragma unroll
        for (int off = 32; off >= 1; off >>= 1) p += __shfl_xor(p, off, 64);
        out[(size_t)B_ * T_ * K_ + tid] = mb + __logf(p);
    }
}

extern "C" void kernel_launch(void* const* d_in, const int* in_sizes, int n_in,
                              void* d_out, int out_size, void* d_ws, size_t ws_size,
                              hipStream_t stream) {
    const int*   x     = (const int*)d_in[0];
    const float* emb   = (const float*)d_in[2];
    const float* w_ih  = (const float*)d_in[3];
    const float* w_hh  = (const float*)d_in[4];
    const float* b_ih  = (const float*)d_in[5];
    const float* b_hh  = (const float*)d_in[6];
    const float* h0    = (const float*)d_in[7];
    const float* c0    = (const float*)d_in[8];
    const float* w_out = (const float*)d_in[9];
    const float* b_out = (const float*)d_in[10];
    const float* trans = (const float*)d_in[11];
    float* out = (float*)d_out;

    // workspace layout (≈199 MB), all low-precision tensors f16
    char* ws = (char*)d_ws;
    _Float16* whh16 = (_Float16*)ws;                              // 2 MB  [L][2][1024][256]
    _Float16* wih16 = (_Float16*)(ws + ((size_t)2 << 20));        // 4 MB  [L][2048][512]
    float*    bsum  = (float*)(ws + ((size_t)6 << 20));           // 16 KB [L][2048]
    _Float16* xe    = (_Float16*)(ws + ((size_t)7 << 20));        // 32 MB [32768][512] (reused as H1)
    _Float16* Zb    = (_Float16*)(ws + ((size_t)39 << 20));       // 128 MB [32768][2048]
    _Float16* H0b   = (_Float16*)(ws + ((size_t)167 << 20));      // 32 MB [32768][512]
    if (ws_size < ((size_t)199 << 20)) return;

    cvt_f16_k<<<1024, 256, 0, stream>>>(w_hh, whh16, 1048576 / 4);
    cvt_f16_k<<<2048, 256, 0, stream>>>(w_ih, wih16, 2097152 / 4);
    bias_sum_k<<<16, 256, 0, stream>>>(b_ih, b_hh, bsum);
    embed_k<<<B_ * T_, 128, 0, stream>>>(x, emb, xe);

    // layer 0
    gemm_bt<<<(32768 / 128) * (2048 / 128), 256, 0, stream>>>(xe, wih16, bsum, Zb, 32768, 2048, 512);
    lstm_layer_k<<<128, 1024, 0, stream>>>(whh16, h0, c0, Zb, H0b);
    // layer 1
    gemm_bt<<<(32768 / 128) * (2048 / 128), 256, 0, stream>>>(H0b, wih16 + (size_t)2048 * 512, bsum + 2048, Zb, 32768, 2048, 512);
    lstm_layer_k<<<128, 1024, 0, stream>>>(whh16 + (size_t)2 * 1024 * 256,
                                           h0 + 2 * B_ * HD_, c0 + 2 * B_ * HD_, Zb, xe /*H1*/);
    // emissions + CRF
    tag_k<<<32768 / 16, 256, 0, stream>>>(xe, w_out, b_out, out);
    crf_k<<<1, 1024, 0, stream>>>(out, trans, out);
}

// Round 3
// 3171.598 us; speedup vs baseline: 1.0615x; 1.0615x over previous
//
#include <hip/hip_runtime.h>

#define B_ 64
#define T_ 512
#define E_ 512
#define HD_ 256
#define H_ 512
#define K_ 16
#define NEG_ (-10000.0f)
#define START_ 13
#define STOP_ 14

typedef unsigned int u32;
using half8  = __attribute__((ext_vector_type(8))) _Float16;
using f32x4  = __attribute__((ext_vector_type(4))) float;
using half2v = __attribute__((ext_vector_type(2))) _Float16;

__device__ __forceinline__ float dot2h(u32 a, u32 b, float c) {
#if __has_builtin(__builtin_amdgcn_fdot2)
    return __builtin_amdgcn_fdot2(__builtin_bit_cast(half2v, a),
                                  __builtin_bit_cast(half2v, b), c, false);
#else
    half2v ha = __builtin_bit_cast(half2v, a), hb = __builtin_bit_cast(half2v, b);
    return c + (float)ha.x * (float)hb.x + (float)ha.y * (float)hb.y;
#endif
}
__device__ __forceinline__ float sigm(float x) { return 1.f / (1.f + __expf(-x)); }
__device__ __forceinline__ float tanh_f(float x) {
    float a = fabsf(x);
    float e = __expf(-2.f * a);
    float t = (1.f - e) / (1.f + e);
    return x < 0.f ? -t : t;
}

// ---------------- converters ----------------
__global__ void cvt_f16_k(const float* __restrict__ src, _Float16* __restrict__ dst, int n4) {
    int i = blockIdx.x * blockDim.x + threadIdx.x;
    if (i < n4) {
        float4 v = ((const float4*)src)[i];
        half2v a; a.x = (_Float16)v.x; a.y = (_Float16)v.y;
        half2v b; b.x = (_Float16)v.z; b.y = (_Float16)v.w;
        ((u32*)dst)[2 * i]     = __builtin_bit_cast(u32, a);
        ((u32*)dst)[2 * i + 1] = __builtin_bit_cast(u32, b);
    }
}
__global__ void bias_sum_k(const float* __restrict__ bih, const float* __restrict__ bhh,
                           float* __restrict__ bs) {
    int i = blockIdx.x * blockDim.x + threadIdx.x;
    if (i < 4096) bs[i] = bih[i] + bhh[i];
}

// ---------------- embedding gather + cast to f16 ----------------
__global__ void embed_k(const int* __restrict__ x, const float* __restrict__ emb,
                        _Float16* __restrict__ xe) {
    int m = blockIdx.x;                  // 0..32767 = b*T + t
    int row = x[m];
    int c = threadIdx.x * 4;             // 128 threads * 4 = 512
    float4 v = *(const float4*)(emb + (size_t)row * E_ + c);
    half2v p0; p0.x = (_Float16)v.x; p0.y = (_Float16)v.y;
    half2v p1; p1.x = (_Float16)v.z; p1.y = (_Float16)v.w;
    u32* dst = (u32*)(xe + (size_t)m * E_) + threadIdx.x * 2;
    dst[0] = __builtin_bit_cast(u32, p0);
    dst[1] = __builtin_bit_cast(u32, p1);
}

// ---------------- f16 MFMA GEMM:  C[m,n] = sum_k A[m,k]*Bw[n,k] + bias[n]  (C f16) -----
__global__ __launch_bounds__(256) void gemm_bt(const _Float16* __restrict__ A,
                                               const _Float16* __restrict__ Bw,
                                               const float* __restrict__ bsum,
                                               _Float16* __restrict__ C,
                                               int M, int N, int Kd) {
    __shared__ __align__(16) _Float16 As[128 * 64];
    __shared__ __align__(16) _Float16 Bs[128 * 64];
    const int nTn = N >> 7;
    const int tm = blockIdx.x / nTn, tn = blockIdx.x % nTn;
    const int tid = threadIdx.x;
    const int lane = tid & 63, wave = tid >> 6;
    const int wr = wave >> 1, wc = wave & 1;      // 2x2 waves of 64x64
    f32x4 acc[4][4];
#pragma unroll
    for (int i = 0; i < 4; ++i)
#pragma unroll
        for (int j = 0; j < 4; ++j) acc[i][j] = f32x4{0.f, 0.f, 0.f, 0.f};
    const int lr = lane & 15, lk = (lane >> 4) * 8;

    for (int k0 = 0; k0 < Kd; k0 += 64) {
#pragma unroll
        for (int r = 0; r < 4; ++r) {
            int c = r * 256 + tid;                     // chunk id, 16B each
            const _Float16* srcA = A + (size_t)(tm * 128 + (c >> 3)) * Kd + k0 + (c & 7) * 8;
            const _Float16* srcB = Bw + (size_t)(tn * 128 + (c >> 3)) * Kd + k0 + (c & 7) * 8;
            _Float16* dA = &As[(size_t)(r * 256 + wave * 64) * 8];
            _Float16* dB = &Bs[(size_t)(r * 256 + wave * 64) * 8];
            __builtin_amdgcn_global_load_lds((const __attribute__((address_space(1))) void*)srcA,
                                             (__attribute__((address_space(3))) void*)dA, 16, 0, 0);
            __builtin_amdgcn_global_load_lds((const __attribute__((address_space(1))) void*)srcB,
                                             (__attribute__((address_space(3))) void*)dB, 16, 0, 0);
        }
        __syncthreads();
#pragma unroll
        for (int kk = 0; kk < 2; ++kk) {
            half8 av[4], bv[4];
#pragma unroll
            for (int i = 0; i < 4; ++i)
                av[i] = *(const half8*)&As[(wr * 64 + i * 16 + lr) * 64 + kk * 32 + lk];
#pragma unroll
            for (int j = 0; j < 4; ++j)
                bv[j] = *(const half8*)&Bs[(wc * 64 + j * 16 + lr) * 64 + kk * 32 + lk];
#pragma unroll
            for (int i = 0; i < 4; ++i)
#pragma unroll
                for (int j = 0; j < 4; ++j)
                    acc[i][j] = __builtin_amdgcn_mfma_f32_16x16x32_f16(av[i], bv[j], acc[i][j], 0, 0, 0);
        }
        __syncthreads();
    }
    const int mq = (lane >> 4) * 4;
#pragma unroll
    for (int i = 0; i < 4; ++i)
#pragma unroll
        for (int j = 0; j < 4; ++j) {
            int m0 = tm * 128 + wr * 64 + i * 16 + mq;
            int n0 = tn * 128 + wc * 64 + j * 16 + lr;
            float bv = bsum[n0];
#pragma unroll
            for (int q = 0; q < 4; ++q)
                C[(size_t)(m0 + q) * N + n0] = (_Float16)(acc[i][j][q] + bv);
        }
}

// ---------------- LSTM recurrence ----------------------------------------------------
// One block per (b, dir), 1024 threads. Thread (wave w, lane l): j = w*16 + (l&15),
// quadrant q = l>>4 owns h-chunk [64q, 64q+64) of the 4 gate rows {j, j+256, j+512, j+768}.
// After a 2-stage shfl_xor butterfly every lane holds the full i,f,g,o preacts for its j
// -> gate math is in-wave, ONE barrier per step. W: 24 u32/row in VGPRs + 8 u32/row in LDS.
// amdgpu_waves_per_eu(4,4): occupancy is structurally 1 block/CU (16 waves, 132 KB LDS);
// pinning 4 waves/EU raises the VGPR budget to 128 so the 96-u32 weight set stays resident.
#define WREG 24
__global__ __launch_bounds__(1024) __attribute__((amdgpu_waves_per_eu(4, 4))) void lstm_layer_k(
    const _Float16* __restrict__ whh,     // [2][1024][256] (this layer)
    const float* __restrict__ h0,         // [2][64][256]
    const float* __restrict__ c0,         // [2][64][256]
    const _Float16* __restrict__ Z,       // [32768][2048] f16 gate preacts (x@Wih + bias)
    _Float16* __restrict__ Hout) {        // [32768][512] f16
    __shared__ __align__(16) uint4 wt[8 * 1024];     // 128 KB weight tails: [slot][tid]
    __shared__ __align__(16) u32 h_sh[2][4][36];     // double-buffered h, 36-u32 padded chunks
    const int tid = threadIdx.x;
    const int b = blockIdx.x >> 1, dir = blockIdx.x & 1;
    const int wv = tid >> 6, l = tid & 63;
    const int jj = l & 15, q = l >> 4;
    const int j = wv * 16 + jj;           // 0..255

    // --- load weights: rows g*256+j, h-cols [64q, 64q+64) ---
    const u32*  wbase  = (const u32*)(whh + (size_t)dir * 1024 * 256);
    const uint4* wbase4 = (const uint4*)wbase;
    u32 w0[WREG], w1[WREG], w2[WREG], w3[WREG];
#pragma unroll
    for (int k = 0; k < WREG; ++k) {
        w0[k] = wbase[(size_t)(0 * 256 + j) * 128 + 32 * q + k];
        w1[k] = wbase[(size_t)(1 * 256 + j) * 128 + 32 * q + k];
        w2[k] = wbase[(size_t)(2 * 256 + j) * 128 + 32 * q + k];
        w3[k] = wbase[(size_t)(3 * 256 + j) * 128 + 32 * q + k];
    }
    // keep-live: mark each weight value as asm-modified so the compiler can neither
    // re-materialize the global loads inside the T-loop nor sink them (learn_hip rule 17)
#pragma unroll
    for (int k = 0; k < WREG; ++k) {
        asm volatile("" : "+v"(w0[k]));
        asm volatile("" : "+v"(w1[k]));
        asm volatile("" : "+v"(w2[k]));
        asm volatile("" : "+v"(w3[k]));
    }
#pragma unroll
    for (int ii = 0; ii < 2; ++ii) {
#pragma unroll
        for (int g = 0; g < 4; ++g)
            wt[(ii * 4 + g) * 1024 + tid] = wbase4[(size_t)(g * 256 + j) * 32 + 8 * q + 6 + ii];
    }
    // --- state init ---
    float c = c0[(size_t)dir * B_ * HD_ + b * HD_ + j];
    if (tid < 128) {
        int p = tid;   // f16-pair index 0..127
        float x0 = h0[(size_t)dir * B_ * HD_ + b * HD_ + 2 * p];
        float x1 = h0[(size_t)dir * B_ * HD_ + b * HD_ + 2 * p + 1];
        half2v hp; hp.x = (_Float16)x0; hp.y = (_Float16)x1;
        h_sh[0][p >> 5][p & 31] = __builtin_bit_cast(u32, hp);
    }
    // --- z: lane (j,q) owns gate q's preact for unit j -> coalesced 64-lane loads ---
    const _Float16* Zlane = Z + (size_t)b * T_ * 2048 + dir * 1024 + q * 256 + j;
    _Float16 zq = (_Float16)0;
    {
        int t0 = dir ? (T_ - 1) : 0;
        zq = Zlane[(size_t)t0 * 2048];
    }
    __syncthreads();

    int cur = 0;
    for (int s = 0; s < T_; ++s) {
        const int t = dir ? (T_ - 1 - s) : s;
        // prefetch next step's z early (hides L2/L3 latency under the dot phase)
        _Float16 zn = (_Float16)0;
        if (s + 1 < T_) {
            const int tn = dir ? (t - 1) : (t + 1);
            zn = Zlane[(size_t)tn * 2048];
        }
        // --- 64-wide quarter dots for 4 gate rows ---
        const uint4* hb = (const uint4*)&h_sh[cur][q][0];
        float a0 = 0.f, a1 = 0.f, a2 = 0.f, a3 = 0.f;
#pragma unroll
        for (int i = 0; i < 6; ++i) {
            uint4 hv = hb[i];
            a0 = dot2h(w0[4 * i], hv.x, a0); a0 = dot2h(w0[4 * i + 1], hv.y, a0);
            a0 = dot2h(w0[4 * i + 2], hv.z, a0); a0 = dot2h(w0[4 * i + 3], hv.w, a0);
            a1 = dot2h(w1[4 * i], hv.x, a1); a1 = dot2h(w1[4 * i + 1], hv.y, a1);
            a1 = dot2h(w1[4 * i + 2], hv.z, a1); a1 = dot2h(w1[4 * i + 3], hv.w, a1);
            a2 = dot2h(w2[4 * i], hv.x, a2); a2 = dot2h(w2[4 * i + 1], hv.y, a2);
            a2 = dot2h(w2[4 * i + 2], hv.z, a2); a2 = dot2h(w2[4 * i + 3], hv.w, a2);
            a3 = dot2h(w3[4 * i], hv.x, a3); a3 = dot2h(w3[4 * i + 1], hv.y, a3);
            a3 = dot2h(w3[4 * i + 2], hv.z, a3); a3 = dot2h(w3[4 * i + 3], hv.w, a3);
        }
#pragma unroll
        for (int ii = 0; ii < 2; ++ii) {
            uint4 hv = hb[6 + ii];
            uint4 tw;
            tw = wt[(ii * 4 + 0) * 1024 + tid];
            a0 = dot2h(tw.x, hv.x, a0); a0 = dot2h(tw.y, hv.y, a0);
            a0 = dot2h(tw.z, hv.z, a0); a0 = dot2h(tw.w, hv.w, a0);
            tw = wt[(ii * 4 + 1) * 1024 + tid];
            a1 = dot2h(tw.x, hv.x, a1); a1 = dot2h(tw.y, hv.y, a1);
            a1 = dot2h(tw.z, hv.z, a1); a1 = dot2h(tw.w, hv.w, a1);
            tw = wt[(ii * 4 + 2) * 1024 + tid];
            a2 = dot2h(tw.x, hv.x, a2); a2 = dot2h(tw.y, hv.y, a2);
            a2 = dot2h(tw.z, hv.z, a2); a2 = dot2h(tw.w, hv.w, a2);
            tw = wt[(ii * 4 + 3) * 1024 + tid];
            a3 = dot2h(tw.x, hv.x, a3); a3 = dot2h(tw.y, hv.y, a3);
            a3 = dot2h(tw.z, hv.z, a3); a3 = dot2h(tw.w, hv.w, a3);
        }
        // fold z (already includes biases) into THIS lane's own gate-q partial;
        // the butterfly over quadrants then delivers it to every copy exactly once
        {
            float zf = (float)zq;
            a0 += (q == 0) ? zf : 0.f;
            a1 += (q == 1) ? zf : 0.f;
            a2 += (q == 2) ? zf : 0.f;
            a3 += (q == 3) ? zf : 0.f;
        }
        a0 += __shfl_xor(a0, 16, 64); a0 += __shfl_xor(a0, 32, 64);
        a1 += __shfl_xor(a1, 16, 64); a1 += __shfl_xor(a1, 32, 64);
        a2 += __shfl_xor(a2, 16, 64); a2 += __shfl_xor(a2, 32, 64);
        a3 += __shfl_xor(a3, 16, 64); a3 += __shfl_xor(a3, 32, 64);
        // gates (i,f,g,o), redundantly in all 4 quadrant copies
        float ig = sigm(a0), fg = sigm(a1), gg = tanh_f(a2), og = sigm(a3);
        c = fg * c + ig * gg;
        float h = og * tanh_f(c);
        if (q == 0) {
            _Float16 hf = (_Float16)h;
            int p = j >> 1;
            ((_Float16*)&h_sh[cur ^ 1][p >> 5][p & 31])[j & 1] = hf;
            Hout[(size_t)(b * T_ + t) * H_ + dir * HD_ + j] = hf;
        }
        zq = zn;
        __syncthreads();
        cur ^= 1;
    }
}

// ---------------- tag scores: out[m,kk] = H[m,:] . w_out[kk,:] + b_out[kk] ----------------
__global__ __launch_bounds__(256) void tag_k(const _Float16* __restrict__ Hs,
                                             const float* __restrict__ wout,
                                             const float* __restrict__ bout,
                                             float* __restrict__ out) {
    const int tid = threadIdx.x;
    const int mi = tid >> 4, kk = tid & 15;
    const int m = blockIdx.x * 16 + mi;
    const uint4* hrow = (const uint4*)(Hs + (size_t)m * H_);
    const float4* wrow = (const float4*)(wout + (size_t)kk * H_);
    float acc = 0.f;
#pragma unroll 8
    for (int i = 0; i < 64; ++i) {
        uint4 hv = hrow[i];
        float4 w0 = wrow[2 * i], w1 = wrow[2 * i + 1];
        half2v p0 = __builtin_bit_cast(half2v, hv.x), p1 = __builtin_bit_cast(half2v, hv.y);
        half2v p2 = __builtin_bit_cast(half2v, hv.z), p3 = __builtin_bit_cast(half2v, hv.w);
        acc += (float)p0.x * w0.x + (float)p0.y * w0.y + (float)p1.x * w0.z + (float)p1.y * w0.w
             + (float)p2.x * w1.x + (float)p2.y * w1.y + (float)p3.x * w1.z + (float)p3.y * w1.w;
    }
    out[(size_t)m * K_ + kk] = acc + bout[kk];
}

// ---------------- CRF forward (faithful to reference's cross-batch sum) ----------------
__global__ __launch_bounds__(1024) void crf_k(const float* __restrict__ tag,
                                              const float* __restrict__ trans,
                                              float* __restrict__ out) {
    __shared__ float albuf[2][64][17];
    const int tid = threadIdx.x;
    const int kn = tid >> 6, b = tid & 63;   // wave = next-tag, lane = batch
    float trow[16];
#pragma unroll
    for (int kp = 0; kp < 16; ++kp) trow[kp] = trans[kn * 16 + kp];
    albuf[0][b][kn] = (kn == START_) ? 0.f : NEG_;
    __syncthreads();
    int cur = 0;
    for (int t = 0; t < T_; ++t) {
        const float feat = tag[(size_t)(b * T_ + t) * K_ + kn];
        float v[16];
        float m = -3.4e38f;
#pragma unroll
        for (int kp = 0; kp < 16; ++kp) {
            v[kp] = albuf[cur][b][kp] + trow[kp];
            m = fmaxf(m, v[kp]);
        }
        float sm = 0.f;
#pragma unroll
        for (int kp = 0; kp < 16; ++kp) sm += __expf(v[kp] - m);
#pragma unroll
        for (int off = 32; off >= 1; off >>= 1) sm += __shfl_xor(sm, off, 64);
        albuf[cur ^ 1][b][kn] = feat + m + __logf(sm);
        __syncthreads();
        cur ^= 1;
    }
    const float term = albuf[cur][b][kn] + trans[STOP_ * 16 + kn];
    albuf[cur ^ 1][b][kn] = term;
    __syncthreads();
    if (tid < 64) {   // all in wave 0
        float mb = -3.4e38f;
#pragma unroll
        for (int k2 = 0; k2 < 16; ++k2) mb = fmaxf(mb, albuf[cur ^ 1][tid][k2]);
        float p = 0.f;
#pragma unroll
        for (int k2 = 0; k2 < 16; ++k2) p += __expf(albuf[cur ^ 1][tid][k2] - mb);
#pragma unroll
        for (int off = 32; off >= 1; off >>= 1) p += __shfl_xor(p, off, 64);
        out[(size_t)B_ * T_ * K_ + tid] = mb + __logf(p);
    }
}

extern "C" void kernel_launch(void* const* d_in, const int* in_sizes, int n_in,
                              void* d_out, int out_size, void* d_ws, size_t ws_size,
                              hipStream_t stream) {
    const int*   x     = (const int*)d_in[0];
    const float* emb   = (const float*)d_in[2];
    const float* w_ih  = (const float*)d_in[3];
    const float* w_hh  = (const float*)d_in[4];
    const float* b_ih  = (const float*)d_in[5];
    const float* b_hh  = (const float*)d_in[6];
    const float* h0    = (const float*)d_in[7];
    const float* c0    = (const float*)d_in[8];
    const float* w_out = (const float*)d_in[9];
    const float* b_out = (const float*)d_in[10];
    const float* trans = (const float*)d_in[11];
    float* out = (float*)d_out;

    // workspace layout (≈199 MB), all low-precision tensors f16
    char* ws = (char*)d_ws;
    _Float16* whh16 = (_Float16*)ws;                              // 2 MB  [L][2][1024][256]
    _Float16* wih16 = (_Float16*)(ws + ((size_t)2 << 20));        // 4 MB  [L][2048][512]
    float*    bsum  = (float*)(ws + ((size_t)6 << 20));           // 16 KB [L][2048]
    _Float16* xe    = (_Float16*)(ws + ((size_t)7 << 20));        // 32 MB [32768][512] (reused as H1)
    _Float16* Zb    = (_Float16*)(ws + ((size_t)39 << 20));       // 128 MB [32768][2048]
    _Float16* H0b   = (_Float16*)(ws + ((size_t)167 << 20));      // 32 MB [32768][512]
    if (ws_size < ((size_t)199 << 20)) return;

    cvt_f16_k<<<1024, 256, 0, stream>>>(w_hh, whh16, 1048576 / 4);
    cvt_f16_k<<<2048, 256, 0, stream>>>(w_ih, wih16, 2097152 / 4);
    bias_sum_k<<<16, 256, 0, stream>>>(b_ih, b_hh, bsum);
    embed_k<<<B_ * T_, 128, 0, stream>>>(x, emb, xe);

    // layer 0
    gemm_bt<<<(32768 / 128) * (2048 / 128), 256, 0, stream>>>(xe, wih16, bsum, Zb, 32768, 2048, 512);
    lstm_layer_k<<<128, 1024, 0, stream>>>(whh16, h0, c0, Zb, H0b);
    // layer 1
    gemm_bt<<<(32768 / 128) * (2048 / 128), 256, 0, stream>>>(H0b, wih16 + (size_t)2048 * 512, bsum + 2048, Zb, 32768, 2048, 512);
    lstm_layer_k<<<128, 1024, 0, stream>>>(whh16 + (size_t)2 * 1024 * 256,
                                           h0 + 2 * B_ * HD_, c0 + 2 * B_ * HD_, Zb, xe /*H1*/);
    // emissions + CRF
    tag_k<<<32768 / 16, 256, 0, stream>>>(xe, w_out, b_out, out);
    crf_k<<<1, 1024, 0, stream>>>(out, trans, out);
}

// Round 4
// 2483.201 us; speedup vs baseline: 1.3558x; 1.2772x over previous
//
#include <hip/hip_runtime.h>

#define B_ 64
#define T_ 512
#define E_ 512
#define HD_ 256
#define H_ 512
#define K_ 16
#define NEG_ (-10000.0f)
#define START_ 13
#define STOP_ 14

typedef unsigned int u32;
using half8  = __attribute__((ext_vector_type(8))) _Float16;
using f32x4  = __attribute__((ext_vector_type(4))) float;
using half2v = __attribute__((ext_vector_type(2))) _Float16;

__device__ __forceinline__ int dot4i8(u32 a, u32 b, int c) {
#if __has_builtin(__builtin_amdgcn_sdot4)
    return __builtin_amdgcn_sdot4((int)a, (int)b, c, false);
#else
    int r = c;
#pragma unroll
    for (int i = 0; i < 4; ++i) {
        int xa = ((int)a << (24 - 8 * i)) >> 24;
        int xb = ((int)b << (24 - 8 * i)) >> 24;
        r += xa * xb;
    }
    return r;
#endif
}
__device__ __forceinline__ float sigm(float x) { return 1.f / (1.f + __expf(-x)); }
__device__ __forceinline__ float tanh_f(float x) {
    float a = fabsf(x);
    float e = __expf(-2.f * a);
    float t = (1.f - e) / (1.f + e);
    return x < 0.f ? -t : t;
}

// ---------------- converters ----------------
__global__ void cvt_f16_k(const float* __restrict__ src, _Float16* __restrict__ dst, int n4) {
    int i = blockIdx.x * blockDim.x + threadIdx.x;
    if (i < n4) {
        float4 v = ((const float4*)src)[i];
        half2v a; a.x = (_Float16)v.x; a.y = (_Float16)v.y;
        half2v b; b.x = (_Float16)v.z; b.y = (_Float16)v.w;
        ((u32*)dst)[2 * i]     = __builtin_bit_cast(u32, a);
        ((u32*)dst)[2 * i + 1] = __builtin_bit_cast(u32, b);
    }
}
__global__ void bias_sum_k(const float* __restrict__ bih, const float* __restrict__ bhh,
                           float* __restrict__ bs) {
    int i = blockIdx.x * blockDim.x + threadIdx.x;
    if (i < 4096) bs[i] = bih[i] + bhh[i];
}

// ---------------- W_hh row-scaled int8 quantization: one 64-thread block per row ------
__global__ void quant_whh_k(const float* __restrict__ whh,   // [4096][256]
                            u32* __restrict__ wq,            // [4096][64] packed i8
                            float* __restrict__ dqw) {       // [4096] dequant = rowmax/127^2
    const int row = blockIdx.x, lane = threadIdx.x;          // 64 lanes
    const float4 v = ((const float4*)(whh + (size_t)row * 256))[lane];
    float m = fmaxf(fmaxf(fabsf(v.x), fabsf(v.y)), fmaxf(fabsf(v.z), fabsf(v.w)));
#pragma unroll
    for (int off = 32; off >= 1; off >>= 1) m = fmaxf(m, __shfl_xor(m, off, 64));
    m = fmaxf(m, 1e-8f);
    const float s = 127.f / m;
    int b0 = ((int)rintf(v.x * s)) & 255;
    int b1 = ((int)rintf(v.y * s)) & 255;
    int b2 = ((int)rintf(v.z * s)) & 255;
    int b3 = ((int)rintf(v.w * s)) & 255;
    wq[(size_t)row * 64 + lane] = (u32)(b0 | (b1 << 8) | (b2 << 16) | (b3 << 24));
    if (lane == 0) dqw[row] = m / (127.f * 127.f);
}

// ---------------- embedding gather + cast to f16 ----------------
__global__ void embed_k(const int* __restrict__ x, const float* __restrict__ emb,
                        _Float16* __restrict__ xe) {
    int m = blockIdx.x;                  // 0..32767 = b*T + t
    int row = x[m];
    int c = threadIdx.x * 4;             // 128 threads * 4 = 512
    float4 v = *(const float4*)(emb + (size_t)row * E_ + c);
    half2v p0; p0.x = (_Float16)v.x; p0.y = (_Float16)v.y;
    half2v p1; p1.x = (_Float16)v.z; p1.y = (_Float16)v.w;
    u32* dst = (u32*)(xe + (size_t)m * E_) + threadIdx.x * 2;
    dst[0] = __builtin_bit_cast(u32, p0);
    dst[1] = __builtin_bit_cast(u32, p1);
}

// ---------------- f16 MFMA GEMM:  C[m,n] = sum_k A[m,k]*Bw[n,k] + bias[n]  (C f16) -----
__global__ __launch_bounds__(256) void gemm_bt(const _Float16* __restrict__ A,
                                               const _Float16* __restrict__ Bw,
                                               const float* __restrict__ bsum,
                                               _Float16* __restrict__ C,
                                               int M, int N, int Kd) {
    __shared__ __align__(16) _Float16 As[128 * 64];
    __shared__ __align__(16) _Float16 Bs[128 * 64];
    const int nTn = N >> 7;
    const int tm = blockIdx.x / nTn, tn = blockIdx.x % nTn;
    const int tid = threadIdx.x;
    const int lane = tid & 63, wave = tid >> 6;
    const int wr = wave >> 1, wc = wave & 1;      // 2x2 waves of 64x64
    f32x4 acc[4][4];
#pragma unroll
    for (int i = 0; i < 4; ++i)
#pragma unroll
        for (int j = 0; j < 4; ++j) acc[i][j] = f32x4{0.f, 0.f, 0.f, 0.f};
    const int lr = lane & 15, lk = (lane >> 4) * 8;

    for (int k0 = 0; k0 < Kd; k0 += 64) {
#pragma unroll
        for (int r = 0; r < 4; ++r) {
            int c = r * 256 + tid;                     // chunk id, 16B each
            const _Float16* srcA = A + (size_t)(tm * 128 + (c >> 3)) * Kd + k0 + (c & 7) * 8;
            const _Float16* srcB = Bw + (size_t)(tn * 128 + (c >> 3)) * Kd + k0 + (c & 7) * 8;
            _Float16* dA = &As[(size_t)(r * 256 + wave * 64) * 8];
            _Float16* dB = &Bs[(size_t)(r * 256 + wave * 64) * 8];
            __builtin_amdgcn_global_load_lds((const __attribute__((address_space(1))) void*)srcA,
                                             (__attribute__((address_space(3))) void*)dA, 16, 0, 0);
            __builtin_amdgcn_global_load_lds((const __attribute__((address_space(1))) void*)srcB,
                                             (__attribute__((address_space(3))) void*)dB, 16, 0, 0);
        }
        __syncthreads();
#pragma unroll
        for (int kk = 0; kk < 2; ++kk) {
            half8 av[4], bv[4];
#pragma unroll
            for (int i = 0; i < 4; ++i)
                av[i] = *(const half8*)&As[(wr * 64 + i * 16 + lr) * 64 + kk * 32 + lk];
#pragma unroll
            for (int j = 0; j < 4; ++j)
                bv[j] = *(const half8*)&Bs[(wc * 64 + j * 16 + lr) * 64 + kk * 32 + lk];
#pragma unroll
            for (int i = 0; i < 4; ++i)
#pragma unroll
                for (int j = 0; j < 4; ++j)
                    acc[i][j] = __builtin_amdgcn_mfma_f32_16x16x32_f16(av[i], bv[j], acc[i][j], 0, 0, 0);
        }
        __syncthreads();
    }
    const int mq = (lane >> 4) * 4;
#pragma unroll
    for (int i = 0; i < 4; ++i)
#pragma unroll
        for (int j = 0; j < 4; ++j) {
            int m0 = tm * 128 + wr * 64 + i * 16 + mq;
            int n0 = tn * 128 + wc * 64 + j * 16 + lr;
            float bv = bsum[n0];
#pragma unroll
            for (int q = 0; q < 4; ++q)
                C[(size_t)(m0 + q) * N + n0] = (_Float16)(acc[i][j][q] + bv);
        }
}

// ---------------- LSTM recurrence, int8 weights --------------------------------------
// One block per (b, dir), 1024 threads. Thread (wave w, lane l): j = w*16 + (l&15),
// quadrant q = l>>4 owns h-cols [64q, 64q+64) of the 4 gate rows {j, j+256, j+512, j+768}.
// Weights are per-row-scaled int8: 32 u32 in VGPRs + 32 u32 in LDS (128 KB) per thread —
// register demand ~58 fits even a 64-VGPR allocation, by construction (R2/R3 lesson:
// the allocator would not grant 128 VGPRs for the f16 version; 512 KB/block can't be
// register-resident, so halve the bytes instead). h is quantized to i8 by producers
// each step (|h|<1 steady-state; h0 gets a dynamic scale folded into the dequant).
__global__ __launch_bounds__(1024) void lstm_layer_k(
    const u32* __restrict__ wq,           // [2][1024][64] packed i8 (this layer)
    const float* __restrict__ dqw,        // [2][1024] rowmax/127^2 (this layer)
    const float* __restrict__ h0,         // [2][64][256]
    const float* __restrict__ c0,         // [2][64][256]
    const _Float16* __restrict__ Z,       // [32768][2048] f16 gate preacts (x@Wih + bias)
    _Float16* __restrict__ Hout) {        // [32768][512] f16
    __shared__ __align__(16) uint4 wl[8][1024];      // 128 KB LDS weight tails
    __shared__ __align__(16) u32 hbuf[2][80];        // double-buffered h_i8 (256 B used)
    __shared__ float redmax[16];
    const int tid = threadIdx.x;
    const int b = blockIdx.x >> 1, dir = blockIdx.x & 1;
    const int wv = tid >> 6, l = tid & 63;
    const int jj = l & 15, q = l >> 4;
    const int j = wv * 16 + jj;           // 0..255

    // --- weights: rows g*256+j, h-col quarter q. u32 k in [0,8) regs, [8,16) LDS ---
    const u32* wbase = wq + (size_t)dir * 1024 * 64;
    uint4 wr0[2], wr1[2], wr2[2], wr3[2];
#pragma unroll
    for (int kk = 0; kk < 2; ++kk) {
        wr0[kk] = ((const uint4*)(wbase + (size_t)(0 * 256 + j) * 64 + q * 16))[kk];
        wr1[kk] = ((const uint4*)(wbase + (size_t)(1 * 256 + j) * 64 + q * 16))[kk];
        wr2[kk] = ((const uint4*)(wbase + (size_t)(2 * 256 + j) * 64 + q * 16))[kk];
        wr3[kk] = ((const uint4*)(wbase + (size_t)(3 * 256 + j) * 64 + q * 16))[kk];
    }
#pragma unroll
    for (int kk = 0; kk < 2; ++kk) {
        wl[0 * 2 + kk][tid] = ((const uint4*)(wbase + (size_t)(0 * 256 + j) * 64 + q * 16))[2 + kk];
        wl[1 * 2 + kk][tid] = ((const uint4*)(wbase + (size_t)(1 * 256 + j) * 64 + q * 16))[2 + kk];
        wl[2 * 2 + kk][tid] = ((const uint4*)(wbase + (size_t)(2 * 256 + j) * 64 + q * 16))[2 + kk];
        wl[3 * 2 + kk][tid] = ((const uint4*)(wbase + (size_t)(3 * 256 + j) * 64 + q * 16))[2 + kk];
    }
    const float dqv0 = dqw[dir * 1024 + 0 * 256 + j];
    const float dqv1 = dqw[dir * 1024 + 1 * 256 + j];
    const float dqv2 = dqw[dir * 1024 + 2 * 256 + j];
    const float dqv3 = dqw[dir * 1024 + 3 * 256 + j];

    // --- state init; h0 needs a dynamic scale (|h0| can exceed 1) ---
    float c = c0[(size_t)dir * B_ * HD_ + b * HD_ + j];
    float h0v = (q == 0) ? h0[(size_t)dir * B_ * HD_ + b * HD_ + j] : 0.f;
    float am = fabsf(h0v);
    am = fmaxf(am, __shfl_xor(am, 1, 64));
    am = fmaxf(am, __shfl_xor(am, 2, 64));
    am = fmaxf(am, __shfl_xor(am, 4, 64));
    am = fmaxf(am, __shfl_xor(am, 8, 64));
    if (l == 0) redmax[wv] = am;
    __syncthreads();
    float m0 = redmax[0];
#pragma unroll
    for (int i = 1; i < 16; ++i) m0 = fmaxf(m0, redmax[i]);
    m0 = fmaxf(m0, 1e-6f);
    if (q == 0) {
        int hq = (int)rintf(h0v * (127.f / m0));
        ((signed char*)&hbuf[0][0])[j] = (signed char)hq;
    }
    // dequant factors: step 0 carries the h0 scale (h ~ hq*m0/127), steady state m=1
    float dqh0 = dqv0 * m0, dqh1 = dqv1 * m0, dqh2 = dqv2 * m0, dqh3 = dqv3 * m0;
    // --- z: lane (j,q) owns gate q's preact for unit j -> coalesced loads ---
    const _Float16* Zlane = Z + (size_t)b * T_ * 2048 + dir * 1024 + q * 256 + j;
    _Float16 zq = Zlane[(size_t)(dir ? T_ - 1 : 0) * 2048];
    __syncthreads();

    int cur = 0;
    for (int s = 0; s < T_; ++s) {
        const int t = dir ? (T_ - 1 - s) : s;
        _Float16 zn = (_Float16)0;
        if (s + 1 < T_) zn = Zlane[(size_t)(dir ? t - 1 : t + 1) * 2048];
        // h_i8 quarter [64q, 64q+64): 16 u32, broadcast reads (conflict-free)
        const uint4* h4 = (const uint4*)&hbuf[cur][q * 16];
        uint4 hA = h4[0], hB = h4[1], hC = h4[2], hD = h4[3];
        int a0 = 0, a1 = 0, a2 = 0, a3 = 0;
        a0 = dot4i8(wr0[0].x, hA.x, a0); a0 = dot4i8(wr0[0].y, hA.y, a0);
        a0 = dot4i8(wr0[0].z, hA.z, a0); a0 = dot4i8(wr0[0].w, hA.w, a0);
        a0 = dot4i8(wr0[1].x, hB.x, a0); a0 = dot4i8(wr0[1].y, hB.y, a0);
        a0 = dot4i8(wr0[1].z, hB.z, a0); a0 = dot4i8(wr0[1].w, hB.w, a0);
        a1 = dot4i8(wr1[0].x, hA.x, a1); a1 = dot4i8(wr1[0].y, hA.y, a1);
        a1 = dot4i8(wr1[0].z, hA.z, a1); a1 = dot4i8(wr1[0].w, hA.w, a1);
        a1 = dot4i8(wr1[1].x, hB.x, a1); a1 = dot4i8(wr1[1].y, hB.y, a1);
        a1 = dot4i8(wr1[1].z, hB.z, a1); a1 = dot4i8(wr1[1].w, hB.w, a1);
        a2 = dot4i8(wr2[0].x, hA.x, a2); a2 = dot4i8(wr2[0].y, hA.y, a2);
        a2 = dot4i8(wr2[0].z, hA.z, a2); a2 = dot4i8(wr2[0].w, hA.w, a2);
        a2 = dot4i8(wr2[1].x, hB.x, a2); a2 = dot4i8(wr2[1].y, hB.y, a2);
        a2 = dot4i8(wr2[1].z, hB.z, a2); a2 = dot4i8(wr2[1].w, hB.w, a2);
        a3 = dot4i8(wr3[0].x, hA.x, a3); a3 = dot4i8(wr3[0].y, hA.y, a3);
        a3 = dot4i8(wr3[0].z, hA.z, a3); a3 = dot4i8(wr3[0].w, hA.w, a3);
        a3 = dot4i8(wr3[1].x, hB.x, a3); a3 = dot4i8(wr3[1].y, hB.y, a3);
        a3 = dot4i8(wr3[1].z, hB.z, a3); a3 = dot4i8(wr3[1].w, hB.w, a3);
        {
            uint4 tw;
            tw = wl[0][tid];
            a0 = dot4i8(tw.x, hC.x, a0); a0 = dot4i8(tw.y, hC.y, a0);
            a0 = dot4i8(tw.z, hC.z, a0); a0 = dot4i8(tw.w, hC.w, a0);
            tw = wl[1][tid];
            a0 = dot4i8(tw.x, hD.x, a0); a0 = dot4i8(tw.y, hD.y, a0);
            a0 = dot4i8(tw.z, hD.z, a0); a0 = dot4i8(tw.w, hD.w, a0);
            tw = wl[2][tid];
            a1 = dot4i8(tw.x, hC.x, a1); a1 = dot4i8(tw.y, hC.y, a1);
            a1 = dot4i8(tw.z, hC.z, a1); a1 = dot4i8(tw.w, hC.w, a1);
            tw = wl[3][tid];
            a1 = dot4i8(tw.x, hD.x, a1); a1 = dot4i8(tw.y, hD.y, a1);
            a1 = dot4i8(tw.z, hD.z, a1); a1 = dot4i8(tw.w, hD.w, a1);
            tw = wl[4][tid];
            a2 = dot4i8(tw.x, hC.x, a2); a2 = dot4i8(tw.y, hC.y, a2);
            a2 = dot4i8(tw.z, hC.z, a2); a2 = dot4i8(tw.w, hC.w, a2);
            tw = wl[5][tid];
            a2 = dot4i8(tw.x, hD.x, a2); a2 = dot4i8(tw.y, hD.y, a2);
            a2 = dot4i8(tw.z, hD.z, a2); a2 = dot4i8(tw.w, hD.w, a2);
            tw = wl[6][tid];
            a3 = dot4i8(tw.x, hC.x, a3); a3 = dot4i8(tw.y, hC.y, a3);
            a3 = dot4i8(tw.z, hC.z, a3); a3 = dot4i8(tw.w, hC.w, a3);
            tw = wl[7][tid];
            a3 = dot4i8(tw.x, hD.x, a3); a3 = dot4i8(tw.y, hD.y, a3);
            a3 = dot4i8(tw.z, hD.z, a3); a3 = dot4i8(tw.w, hD.w, a3);
        }
        // dequant; fold this lane's own-gate z before the quadrant butterfly
        float zf = (float)zq;
        float f0 = (float)a0 * dqh0 + ((q == 0) ? zf : 0.f);
        float f1 = (float)a1 * dqh1 + ((q == 1) ? zf : 0.f);
        float f2 = (float)a2 * dqh2 + ((q == 2) ? zf : 0.f);
        float f3 = (float)a3 * dqh3 + ((q == 3) ? zf : 0.f);
        f0 += __shfl_xor(f0, 16, 64); f0 += __shfl_xor(f0, 32, 64);
        f1 += __shfl_xor(f1, 16, 64); f1 += __shfl_xor(f1, 32, 64);
        f2 += __shfl_xor(f2, 16, 64); f2 += __shfl_xor(f2, 32, 64);
        f3 += __shfl_xor(f3, 16, 64); f3 += __shfl_xor(f3, 32, 64);
        float ig = sigm(f0), fg = sigm(f1), gg = tanh_f(f2), og = sigm(f3);
        c = fg * c + ig * gg;
        float h = og * tanh_f(c);
        if (q == 0) {
            Hout[(size_t)(b * T_ + t) * H_ + dir * HD_ + j] = (_Float16)h;
            ((signed char*)&hbuf[cur ^ 1][0])[j] = (signed char)(int)rintf(h * 127.f);
        }
        if (s == 0) { dqh0 = dqv0; dqh1 = dqv1; dqh2 = dqv2; dqh3 = dqv3; }
        zq = zn;
        __syncthreads();
        cur ^= 1;
    }
}

// ---------------- tag scores: out[m,kk] = H[m,:] . w_out[kk,:] + b_out[kk] ----------------
__global__ __launch_bounds__(256) void tag_k(const _Float16* __restrict__ Hs,
                                             const float* __restrict__ wout,
                                             const float* __restrict__ bout,
                                             float* __restrict__ out) {
    const int tid = threadIdx.x;
    const int mi = tid >> 4, kk = tid & 15;
    const int m = blockIdx.x * 16 + mi;
    const uint4* hrow = (const uint4*)(Hs + (size_t)m * H_);
    const float4* wrow = (const float4*)(wout + (size_t)kk * H_);
    float acc = 0.f;
#pragma unroll 8
    for (int i = 0; i < 64; ++i) {
        uint4 hv = hrow[i];
        float4 w0 = wrow[2 * i], w1 = wrow[2 * i + 1];
        half2v p0 = __builtin_bit_cast(half2v, hv.x), p1 = __builtin_bit_cast(half2v, hv.y);
        half2v p2 = __builtin_bit_cast(half2v, hv.z), p3 = __builtin_bit_cast(half2v, hv.w);
        acc += (float)p0.x * w0.x + (float)p0.y * w0.y + (float)p1.x * w0.z + (float)p1.y * w0.w
             + (float)p2.x * w1.x + (float)p2.y * w1.y + (float)p3.x * w1.z + (float)p3.y * w1.w;
    }
    out[(size_t)m * K_ + kk] = acc + bout[kk];
}

// ---------------- CRF forward (faithful to reference's cross-batch sum) ----------------
__global__ __launch_bounds__(1024) void crf_k(const float* __restrict__ tag,
                                              const float* __restrict__ trans,
                                              float* __restrict__ out) {
    __shared__ float albuf[2][64][17];
    const int tid = threadIdx.x;
    const int kn = tid >> 6, b = tid & 63;   // wave = next-tag, lane = batch
    float trow[16];
#pragma unroll
    for (int kp = 0; kp < 16; ++kp) trow[kp] = trans[kn * 16 + kp];
    albuf[0][b][kn] = (kn == START_) ? 0.f : NEG_;
    __syncthreads();
    int cur = 0;
    for (int t = 0; t < T_; ++t) {
        const float feat = tag[(size_t)(b * T_ + t) * K_ + kn];
        float v[16];
        float m = -3.4e38f;
#pragma unroll
        for (int kp = 0; kp < 16; ++kp) {
            v[kp] = albuf[cur][b][kp] + trow[kp];
            m = fmaxf(m, v[kp]);
        }
        float sm = 0.f;
#pragma unroll
        for (int kp = 0; kp < 16; ++kp) sm += __expf(v[kp] - m);
#pragma unroll
        for (int off = 32; off >= 1; off >>= 1) sm += __shfl_xor(sm, off, 64);
        albuf[cur ^ 1][b][kn] = feat + m + __logf(sm);
        __syncthreads();
        cur ^= 1;
    }
    const float term = albuf[cur][b][kn] + trans[STOP_ * 16 + kn];
    albuf[cur ^ 1][b][kn] = term;
    __syncthreads();
    if (tid < 64) {   // all in wave 0
        float mb = -3.4e38f;
#pragma unroll
        for (int k2 = 0; k2 < 16; ++k2) mb = fmaxf(mb, albuf[cur ^ 1][tid][k2]);
        float p = 0.f;
#pragma unroll
        for (int k2 = 0; k2 < 16; ++k2) p += __expf(albuf[cur ^ 1][tid][k2] - mb);
#pragma unroll
        for (int off = 32; off >= 1; off >>= 1) p += __shfl_xor(p, off, 64);
        out[(size_t)B_ * T_ * K_ + tid] = mb + __logf(p);
    }
}

extern "C" void kernel_launch(void* const* d_in, const int* in_sizes, int n_in,
                              void* d_out, int out_size, void* d_ws, size_t ws_size,
                              hipStream_t stream) {
    const int*   x     = (const int*)d_in[0];
    const float* emb   = (const float*)d_in[2];
    const float* w_ih  = (const float*)d_in[3];
    const float* w_hh  = (const float*)d_in[4];
    const float* b_ih  = (const float*)d_in[5];
    const float* b_hh  = (const float*)d_in[6];
    const float* h0    = (const float*)d_in[7];
    const float* c0    = (const float*)d_in[8];
    const float* w_out = (const float*)d_in[9];
    const float* b_out = (const float*)d_in[10];
    const float* trans = (const float*)d_in[11];
    float* out = (float*)d_out;

    // workspace layout (≈199 MB)
    char* ws = (char*)d_ws;
    u32*      wq    = (u32*)ws;                                   // 1 MB  [L][2][1024][64] i8-packed
    float*    dqw   = (float*)(ws + ((size_t)1 << 20));           // 16 KB [L][2][1024]
    _Float16* wih16 = (_Float16*)(ws + ((size_t)2 << 20));        // 4 MB  [L][2048][512]
    float*    bsum  = (float*)(ws + ((size_t)6 << 20));           // 16 KB [L][2048]
    _Float16* xe    = (_Float16*)(ws + ((size_t)7 << 20));        // 32 MB [32768][512] (reused as H1)
    _Float16* Zb    = (_Float16*)(ws + ((size_t)39 << 20));       // 128 MB [32768][2048]
    _Float16* H0b   = (_Float16*)(ws + ((size_t)167 << 20));      // 32 MB [32768][512]
    if (ws_size < ((size_t)199 << 20)) return;

    quant_whh_k<<<4096, 64, 0, stream>>>(w_hh, wq, dqw);
    cvt_f16_k<<<2048, 256, 0, stream>>>(w_ih, wih16, 2097152 / 4);
    bias_sum_k<<<16, 256, 0, stream>>>(b_ih, b_hh, bsum);
    embed_k<<<B_ * T_, 128, 0, stream>>>(x, emb, xe);

    // layer 0
    gemm_bt<<<(32768 / 128) * (2048 / 128), 256, 0, stream>>>(xe, wih16, bsum, Zb, 32768, 2048, 512);
    lstm_layer_k<<<128, 1024, 0, stream>>>(wq, dqw, h0, c0, Zb, H0b);
    // layer 1
    gemm_bt<<<(32768 / 128) * (2048 / 128), 256, 0, stream>>>(H0b, wih16 + (size_t)2048 * 512, bsum + 2048, Zb, 32768, 2048, 512);
    lstm_layer_k<<<128, 1024, 0, stream>>>(wq + (size_t)2048 * 64, dqw + 2048,
                                           h0 + 2 * B_ * HD_, c0 + 2 * B_ * HD_, Zb, xe /*H1*/);
    // emissions + CRF
    tag_k<<<32768 / 16, 256, 0, stream>>>(xe, w_out, b_out, out);
    crf_k<<<1, 1024, 0, stream>>>(out, trans, out);
}